// Round 1
// baseline (7160.517 us; speedup 1.0000x reference)
//
#include <hip/hip_runtime.h>
#include <stdint.h>

// SPIRiT CG reconstruction, fp32 direct-conv implementation.
// Fields are planar complex: f[c*NPIX + i*384 + j] as float2.
// Weights laid out W[(ci*81 + p*9 + q)*16 + co] as float2 so the 16 co values
// for a fixed (ci,p,q) are contiguous.

#define MM 384
#define NPIX (MM*MM)          // 147456
#define NC 16
#define N2 (NC*NPIX)          // 2359296 complex elements per field
#define NRED 512              // reduction blocks (two-stage deterministic)

__device__ __forceinline__ float2 block_reduce2(float2 v) {
    #pragma unroll
    for (int off = 32; off > 0; off >>= 1) {
        v.x += __shfl_down(v.x, off);
        v.y += __shfl_down(v.y, off);
    }
    __shared__ float2 tmp[8];
    const int wid = threadIdx.x >> 6, lid = threadIdx.x & 63;
    if (lid == 0) tmp[wid] = v;
    __syncthreads();
    if (threadIdx.x == 0) {
        const int nw = blockDim.x >> 6;
        for (int i = 1; i < nw; ++i) { v.x += tmp[i].x; v.y += tmp[i].y; }
    }
    return v;   // valid on thread 0 only
}

// Build Wf[co,ci,p,q] = K[q,p,ci,co] and Wb[o,i,p,q] = conj(Wf[i,o,8-p,8-q]),
// both stored as W[(in*81 + p*9 + q)*16 + out].
__global__ void prep_weights(const float* __restrict__ kr, const float* __restrict__ ki,
                             float2* __restrict__ Wf, float2* __restrict__ Wb) {
    const int e = blockIdx.x * blockDim.x + threadIdx.x;
    if (e >= 81 * 256) return;     // 20736 = 16*9*9*16
    const int co = e & 15;
    const int r1 = e >> 4;
    const int q  = r1 % 9;
    const int r2 = r1 / 9;
    const int p  = r2 % 9;
    const int ci = r2 / 9;
    // Wf[co,ci,p,q] = kern[(q*9+p)*256 + ci*16 + co]
    const int sf = (q*9 + p)*256 + ci*16 + co;
    Wf[e] = make_float2(kr[sf], ki[sf]);
    // Wb[o=co, i=ci, p, q] = conj(kern[((8-q)*9+(8-p))*256 + co*16 + ci])
    const int sb = ((8-q)*9 + (8-p))*256 + co*16 + ci;
    Wb[e] = make_float2(kr[sb], -ki[sb]);
}

// ws field (= initial b, updated in place) + sampling mask bits.
__global__ void prep_fields(const float* __restrict__ ks, const float* __restrict__ prev,
                            float2* __restrict__ wsf, uint8_t* __restrict__ mask8) {
    const int pix = blockIdx.x * blockDim.x + threadIdx.x;
    if (pix >= NPIX) return;
    #pragma unroll
    for (int c = 0; c < 16; ++c) {
        const float krr = ks[pix*32 + c];
        const float kii = ks[pix*32 + c + 16];
        mask8[c*NPIX + pix] = (krr != 0.f || kii != 0.f) ? 1 : 0;
        wsf[c*NPIX + pix] = make_float2(prev[pix*32 + c], prev[pix*32 + c + 16]);
    }
}

// Direct complex conv 9x9, 16->16 channels, zero-pad 4, fused epilogues.
// MODE 0: out = conv(x) - x                                   (b1 = (G-I)x)
// MODE 1: out = conv(x) - x + mask(p) + am*p   (q = ATA(p)+am*p; x = b1, aux = p)
// MODE 2: out = out2 = mask(kk) + am*zc - (conv(x) - x) - mask(ws) - am*ws
//                                            (p0 = r0; x = b1(ws), aux = ws)
template<int MODE>
__global__ __launch_bounds__(256)
void conv9(const float2* __restrict__ x, const float2* __restrict__ W,
           float2* __restrict__ out, float2* __restrict__ out2,
           const float2* __restrict__ aux,
           const float* __restrict__ ks, const float* __restrict__ z,
           const uint8_t* __restrict__ mask8, const float* __restrict__ miu)
{
    __shared__ float2 Xs[16][25];     // (8+8) rows x (16+8) cols, +1 col pad
    __shared__ float2 Wsh[81*16];     // one ci's weights: [(p*9+q)*16 + co]

    const int t  = threadIdx.x;
    const int bi = blockIdx.x;
    const int i0 = (bi / 24) * 8;     // 48 row-tiles
    const int j0 = (bi % 24) * 16;    // 24 col-tiles
    const int pg  = t & 63;           // pixel group: 2 horizontally-adjacent pixels
    const int cg  = t >> 6;           // co group: 4 channels
    const int row = pg >> 3;          // 0..7
    const int c2  = (pg & 7) * 2;     // 0,2,..,14

    float2 acc[2][4];
    #pragma unroll
    for (int a = 0; a < 2; ++a)
        #pragma unroll
        for (int k = 0; k < 4; ++k) acc[a][k] = make_float2(0.f, 0.f);

    for (int ci = 0; ci < 16; ++ci) {
        __syncthreads();
        // stage input slab (rows i0-4 .. i0+11, cols j0-4 .. j0+19), zero halo
        for (int e = t; e < 16*24; e += 256) {
            const int rr = e / 24, cc = e % 24;
            const int gi = i0 - 4 + rr, gj = j0 - 4 + cc;
            float2 v = make_float2(0.f, 0.f);
            if ((unsigned)gi < MM && (unsigned)gj < MM)
                v = x[ci*NPIX + gi*MM + gj];
            Xs[rr][cc] = v;
        }
        // stage this ci's weights
        for (int e = t; e < 81*16; e += 256)
            Wsh[e] = W[ci*81*16 + e];
        __syncthreads();

        #pragma unroll 1
        for (int p = 0; p < 9; ++p) {
            #pragma unroll
            for (int q = 0; q < 9; ++q) {
                const float2 x0 = Xs[row + p][c2 + q];
                const float2 x1 = Xs[row + p][c2 + q + 1];
                #pragma unroll
                for (int k = 0; k < 4; ++k) {
                    const float2 w = Wsh[(p*9 + q)*16 + cg*4 + k];
                    acc[0][k].x = fmaf(x0.x, w.x, fmaf(-x0.y, w.y, acc[0][k].x));
                    acc[0][k].y = fmaf(x0.x, w.y, fmaf( x0.y, w.x, acc[0][k].y));
                    acc[1][k].x = fmaf(x1.x, w.x, fmaf(-x1.y, w.y, acc[1][k].x));
                    acc[1][k].y = fmaf(x1.x, w.y, fmaf( x1.y, w.x, acc[1][k].y));
                }
            }
        }
    }

    const int gi = i0 + row;
    const float am = (MODE >= 1) ? fabsf(miu[0]) : 0.f;
    #pragma unroll
    for (int a = 0; a < 2; ++a) {
        const int gj  = j0 + c2 + a;
        const int pix = gi*MM + gj;
        #pragma unroll
        for (int k = 0; k < 4; ++k) {
            const int co  = cg*4 + k;
            const int idx = co*NPIX + pix;
            float2 r = acc[a][k];
            if (MODE == 0) {
                const float2 xc = x[idx];
                r.x -= xc.x; r.y -= xc.y;
                out[idx] = r;
            } else if (MODE == 1) {
                const float2 tc = x[idx];
                const float2 pc = aux[idx];
                const float mv = mask8[idx] ? 1.f : 0.f;
                r.x += -tc.x + (mv + am) * pc.x;
                r.y += -tc.y + (mv + am) * pc.y;
                out[idx] = r;
            } else {
                const float2 tc = x[idx];
                const float2 wc = aux[idx];
                const float mv = mask8[idx] ? 1.f : 0.f;
                const float krr = ks[pix*32 + co], kii = ks[pix*32 + co + 16];
                const float zr  = z[pix*32 + co],  zi  = z[pix*32 + co + 16];
                float2 pv;
                pv.x = mv*krr + am*zr - (r.x - tc.x) - (mv + am)*wc.x;
                pv.y = mv*kii + am*zi - (r.y - tc.y) - (mv + am)*wc.y;
                out[idx]  = pv;
                out2[idx] = pv;
            }
        }
    }
}

__global__ void dot_rr(const float2* __restrict__ p, float2* __restrict__ partials) {
    float2 s = make_float2(0.f, 0.f);
    for (int e = blockIdx.x*256 + threadIdx.x; e < N2; e += NRED*256) {
        const float2 v = p[e];
        s.x += v.x*v.x + v.y*v.y;
    }
    s = block_reduce2(s);
    if (threadIdx.x == 0) partials[blockIdx.x] = s;
}

__global__ void finalize_rr(const float2* __restrict__ partials, float* __restrict__ scal) {
    float2 v = partials[threadIdx.x];
    v = block_reduce2(v);
    if (threadIdx.x == 0) scal[0] = v.x;   // rr
}

// sum q * conj(p)
__global__ void dot_qp(const float2* __restrict__ q, const float2* __restrict__ p,
                       float2* __restrict__ partials) {
    float2 s = make_float2(0.f, 0.f);
    for (int e = blockIdx.x*256 + threadIdx.x; e < N2; e += NRED*256) {
        const float2 qv = q[e], pv = p[e];
        s.x += qv.x*pv.x + qv.y*pv.y;
        s.y += qv.y*pv.x - qv.x*pv.y;
    }
    s = block_reduce2(s);
    if (threadIdx.x == 0) partials[blockIdx.x] = s;
}

__global__ void finalize_alpha(const float2* __restrict__ partials, float* __restrict__ scal) {
    float2 v = partials[threadIdx.x];
    v = block_reduce2(v);
    if (threadIdx.x == 0) {
        const float rr = scal[0];
        const float d  = v.x*v.x + v.y*v.y;
        scal[1] =  rr * v.x / d;   // alpha.re
        scal[2] = -rr * v.y / d;   // alpha.im
    }
}

__global__ void update_br(float2* __restrict__ b, const float2* __restrict__ p,
                          float2* __restrict__ r, const float2* __restrict__ q,
                          const float* __restrict__ scal, float2* __restrict__ partials) {
    const float ar = scal[1], ai = scal[2];
    float2 s = make_float2(0.f, 0.f);
    for (int e = blockIdx.x*256 + threadIdx.x; e < N2; e += NRED*256) {
        const float2 pv = p[e], qv = q[e];
        float2 bv = b[e], rv = r[e];
        bv.x += ar*pv.x - ai*pv.y;
        bv.y += ar*pv.y + ai*pv.x;
        rv.x -= ar*qv.x - ai*qv.y;
        rv.y -= ar*qv.y + ai*qv.x;
        b[e] = bv; r[e] = rv;
        s.x += rv.x*rv.x + rv.y*rv.y;
    }
    s = block_reduce2(s);
    if (threadIdx.x == 0) partials[blockIdx.x] = s;
}

__global__ void finalize_beta(const float2* __restrict__ partials, float* __restrict__ scal) {
    float2 v = partials[threadIdx.x];
    v = block_reduce2(v);
    if (threadIdx.x == 0) {
        const float rn = v.x;
        scal[3] = rn / scal[0];   // beta
        scal[0] = rn;             // rr for next iteration
    }
}

__global__ void update_p(float2* __restrict__ p, const float2* __restrict__ r,
                         const float* __restrict__ scal) {
    const float beta = scal[3];
    const int e = blockIdx.x*256 + threadIdx.x;
    if (e < N2) {
        const float2 pv = p[e], rv = r[e];
        p[e] = make_float2(rv.x + beta*pv.x, rv.y + beta*pv.y);
    }
}

__global__ void pack_out(const float2* __restrict__ b, float* __restrict__ out) {
    const int e = blockIdx.x*256 + threadIdx.x;   // over 32*NPIX
    if (e >= 32*NPIX) return;
    const int pix = e >> 5;
    const int cc  = e & 31;
    const float2 v = b[(cc & 15)*NPIX + pix];
    out[e] = (cc < 16) ? v.x : v.y;
}

extern "C" void kernel_launch(void* const* d_in, const int* in_sizes, int n_in,
                              void* d_out, int out_size, void* d_ws, size_t ws_size,
                              hipStream_t stream) {
    const float* z    = (const float*)d_in[0];
    const float* ks   = (const float*)d_in[1];
    const float* kr   = (const float*)d_in[2];
    const float* ki   = (const float*)d_in[3];
    const float* prev = (const float*)d_in[5];
    const float* miu  = (const float*)d_in[6];
    float* out = (float*)d_out;

    char* w = (char*)d_ws;
    const size_t FB = (size_t)N2 * sizeof(float2);   // 18,874,368 B per field
    float2* wsf = (float2*)w; w += FB;               // ws; aliased as b (updated in place)
    float2* pf  = (float2*)w; w += FB;
    float2* rf  = (float2*)w; w += FB;
    float2* qf  = (float2*)w; w += FB;
    float2* tf  = (float2*)w; w += FB;               // b1 intermediate
    float2* Wf  = (float2*)w; w += (size_t)20736 * sizeof(float2);
    float2* Wb  = (float2*)w; w += (size_t)20736 * sizeof(float2);
    uint8_t* mask8 = (uint8_t*)w; w += N2;
    w = (char*)(((uintptr_t)w + 255) & ~(uintptr_t)255);
    float2* partials = (float2*)w; w += NRED * sizeof(float2);
    float*  scal     = (float*)w;                    // [rr, alpha.re, alpha.im, beta]

    prep_weights<<<81, 256, 0, stream>>>(kr, ki, Wf, Wb);
    prep_fields<<<576, 256, 0, stream>>>(ks, prev, wsf, mask8);

    // setup: t = (G-I) ws ;  p0 = r0 = mask(kk) + am*zc - ATA(ws) - am*ws
    conv9<0><<<1152, 256, 0, stream>>>(wsf, Wf, tf, nullptr, nullptr, nullptr, nullptr, nullptr, nullptr);
    conv9<2><<<1152, 256, 0, stream>>>(tf, Wb, pf, rf, wsf, ks, z, mask8, miu);
    dot_rr<<<NRED, 256, 0, stream>>>(pf, partials);
    finalize_rr<<<1, NRED, 0, stream>>>(partials, scal);

    for (int it = 0; it < 10; ++it) {
        conv9<0><<<1152, 256, 0, stream>>>(pf, Wf, tf, nullptr, nullptr, nullptr, nullptr, nullptr, nullptr);
        conv9<1><<<1152, 256, 0, stream>>>(tf, Wb, qf, nullptr, pf, nullptr, nullptr, mask8, miu);
        dot_qp<<<NRED, 256, 0, stream>>>(qf, pf, partials);
        finalize_alpha<<<1, NRED, 0, stream>>>(partials, scal);
        update_br<<<NRED, 256, 0, stream>>>(wsf, pf, rf, qf, scal, partials);
        finalize_beta<<<1, NRED, 0, stream>>>(partials, scal);
        update_p<<<9216, 256, 0, stream>>>(pf, rf, scal);
    }

    pack_out<<<18432, 256, 0, stream>>>(wsf, out);
}

// Round 2
// 4764.631 us; speedup vs baseline: 1.5028x; 1.5028x over previous
//
#include <hip/hip_runtime.h>
#include <stdint.h>

// SPIRiT CG reconstruction. Convs via bf16 hi/lo-split MFMA (3 products:
// Wh*Xh + Wl*Xh + Wh*Xl), per-tap implicit GEMM: M=16 c_out, N=16 pixels,
// K=32 = 16 c_in x {re,im}. Fields are planar complex float2 f[c][384*384].

#define MM 384
#define NPIX (MM*MM)          // 147456
#define N2 (16*NPIX)          // complex elements per field
#define NRED 512
#define NCBLK 576             // conv grid: 48 row-tiles x 12 col-tiles (8x32 px)

typedef __attribute__((ext_vector_type(8))) short short8;
typedef __attribute__((ext_vector_type(4))) float f32x4;
typedef unsigned int u32;

__device__ __forceinline__ float2 block_reduce2(float2 v) {
    #pragma unroll
    for (int off = 32; off > 0; off >>= 1) {
        v.x += __shfl_down(v.x, off);
        v.y += __shfl_down(v.y, off);
    }
    __shared__ float2 tmp[8];
    const int wid = threadIdx.x >> 6, lid = threadIdx.x & 63;
    if (lid == 0) tmp[wid] = v;
    __syncthreads();
    if (threadIdx.x == 0) {
        const int nw = blockDim.x >> 6;
        for (int i = 1; i < nw; ++i) { v.x += tmp[i].x; v.y += tmp[i].y; }
    }
    return v;
}

// hi/lo bf16 split of two floats, packed as one u32 each (elem0 lo half).
__device__ __forceinline__ void split_pair(float a, float b, u32& hw, u32& lw) {
    const u32 ua = __float_as_uint(a), ub = __float_as_uint(b);
    const u32 ha = ua & 0xFFFF0000u, hb = ub & 0xFFFF0000u;
    const float la = a - __uint_as_float(ha);
    const float lb = b - __uint_as_float(hb);
    hw = hb | (ha >> 16);
    lw = (__float_as_uint(lb) & 0xFFFF0000u) | (__float_as_uint(la) >> 16);
}

// Weight fragment builder. A_half0[co][kc] = [Wr | -Wi], A_half1 = [Wi | Wr]
// (kc<16: ci real rows, kc>=16: ci imag rows). Fragment block layout:
// [dir][p*9+q][pt(h/l)][hf][lane64][4 u32], lane = co + 16*kgroup.
__global__ void prep_weights(const float* __restrict__ kr, const float* __restrict__ ki,
                             u32* __restrict__ wbuf) {
    const int e = blockIdx.x * 256 + threadIdx.x;
    if (e >= 20736) return;
    const int lane = e & 63;
    int r = e >> 6;
    const int hf = r & 1; r >>= 1;
    const int q = r % 9; r /= 9;
    const int p = r % 9; r /= 9;
    const int dir = r;
    const int co = lane & 15, g = lane >> 4;
    float vv[8];
    #pragma unroll
    for (int t = 0; t < 8; ++t) {
        const int kc = 8 * g + t;
        const int ci = kc & 15;
        const int isI = kc >> 4;
        int sidx;
        if (dir == 0) sidx = (q*9 + p)*256 + ci*16 + co;          // Wf[co,ci,p,q]=K[q,p,ci,co]
        else          sidx = ((8-q)*9 + (8-p))*256 + co*16 + ci;  // Wb = conj flip swap
        const float wr = kr[sidx];
        const float wi = (dir == 0) ? ki[sidx] : -ki[sidx];
        vv[t] = (hf == 0) ? (isI ? -wi : wr) : (isI ? wr : wi);
    }
    u32 hw[4], lw[4];
    #pragma unroll
    for (int t = 0; t < 4; ++t) split_pair(vv[2*t], vv[2*t+1], hw[t], lw[t]);
    const int b0 = dir*324 + (p*9 + q)*4 + hf;       // pt=0
    u32* o0 = wbuf + (size_t)b0*256 + lane*4;
    u32* o1 = o0 + 2*256;                            // pt=1
    *(uint4*)o0 = make_uint4(hw[0], hw[1], hw[2], hw[3]);
    *(uint4*)o1 = make_uint4(lw[0], lw[1], lw[2], lw[3]);
}

__global__ void prep_fields(const float* __restrict__ ks, const float* __restrict__ prev,
                            float2* __restrict__ wsf, uint8_t* __restrict__ mask8) {
    const int pix = blockIdx.x * blockDim.x + threadIdx.x;
    if (pix >= NPIX) return;
    #pragma unroll
    for (int c = 0; c < 16; ++c) {
        const float krr = ks[(size_t)pix*32 + c];
        const float kii = ks[(size_t)pix*32 + c + 16];
        mask8[(size_t)c*NPIX + pix] = (krr != 0.f || kii != 0.f) ? 1 : 0;
        wsf[(size_t)c*NPIX + pix] = make_float2(prev[(size_t)pix*32 + c], prev[(size_t)pix*32 + c + 16]);
    }
}

// MODE 0: out = conv(x) - x
// MODE 1: out = conv(x) - x + (mask+am)*aux ; partial += out*conj(aux)
// MODE 2: out=out2 = mask*kk + am*z - (conv(x)-x) - (mask+am)*aux ; partial += |out|^2
template<int MODE>
__global__ __launch_bounds__(256)
void conv9(const float2* __restrict__ x, const u32* __restrict__ Wd,
           float2* __restrict__ out, float2* __restrict__ out2,
           const float2* __restrict__ aux, const float* __restrict__ ks,
           const float* __restrict__ z, const uint8_t* __restrict__ mask8,
           const float* __restrict__ miu, float2* __restrict__ partials)
{
    __shared__ __align__(16) char Xs[40960];   // 8 rows x 40 cols x 8 slots x 16B
    __shared__ __align__(16) char Wl[20480];   // up to 5 taps x 4 blocks x 1KB
    const int t = threadIdx.x;
    const int bi = blockIdx.x;
    const int i0 = (bi / 12) * 8;
    const int j0 = (bi % 12) * 32;
    const int w = t >> 6, lane = t & 63;
    const int m = lane & 15, g = lane >> 4;

    f32x4 acc[4][2];
    #pragma unroll
    for (int a = 0; a < 4; ++a)
        #pragma unroll
        for (int h = 0; h < 2; ++h) acc[a][h] = (f32x4){0.f, 0.f, 0.f, 0.f};

    for (int p = 0; p < 9; ++p) {
        __syncthreads();
        // ---- stage X rows for this p: input row = i0+p-4+row, cols j0-4..j0+35
        const int rg0 = i0 + p - 4;
        for (int u = t; u < 640; u += 256) {
            const int col = u % 40;
            int rest = u / 40;
            const int row = rest >> 1;
            const int cih = rest & 1;
            const int row_g = rg0 + row;
            const int col_g = j0 - 4 + col;
            const bool valid = ((unsigned)row_g < MM) && ((unsigned)col_g < MM);
            float2 v[8];
            const float2* src = x + (size_t)(cih*8)*NPIX + (size_t)row_g*MM + col_g;
            #pragma unroll
            for (int e = 0; e < 8; ++e)
                v[e] = valid ? src[(size_t)e*NPIX] : make_float2(0.f, 0.f);
            u32 reh[4], rel[4], imh[4], iml[4];
            #pragma unroll
            for (int k2 = 0; k2 < 4; ++k2) {
                split_pair(v[2*k2].x, v[2*k2+1].x, reh[k2], rel[k2]);
                split_pair(v[2*k2].y, v[2*k2+1].y, imh[k2], iml[k2]);
            }
            const int c7 = col_g & 7;   // slot XOR swizzle key (consistent with reads)
            char* pb = Xs + (size_t)(row*40 + col)*128;
            *(uint4*)(pb + (((0 + cih) ^ c7) << 4)) = make_uint4(reh[0], reh[1], reh[2], reh[3]);
            *(uint4*)(pb + (((2 + cih) ^ c7) << 4)) = make_uint4(imh[0], imh[1], imh[2], imh[3]);
            *(uint4*)(pb + (((4 + cih) ^ c7) << 4)) = make_uint4(rel[0], rel[1], rel[2], rel[3]);
            *(uint4*)(pb + (((6 + cih) ^ c7) << 4)) = make_uint4(iml[0], iml[1], iml[2], iml[3]);
        }
        // ---- stage W taps q=0..4
        {
            const char* wsrc = (const char*)Wd + (size_t)(p*9)*4096;
            for (int off = t*16; off < 5*4096; off += 4096)
                *(uint4*)(Wl + off) = *(const uint4*)(wsrc + off);
        }
        __syncthreads();
        // ---- compute taps, chunked to fit W in LDS
        #pragma unroll 1
        for (int half = 0; half < 2; ++half) {
            const int qbase = half ? 5 : 0;
            const int ntaps = half ? 4 : 5;
            for (int qi = 0; qi < ntaps; ++qi) {
                const int q = qbase + qi;
                short8 wa[2][2];
                #pragma unroll
                for (int pt = 0; pt < 2; ++pt)
                    #pragma unroll
                    for (int hf = 0; hf < 2; ++hf)
                        wa[pt][hf] = *(const short8*)(Wl + ((qi*4 + pt*2 + hf) << 10) + (lane << 4));
                short8 xb[4][2];
                #pragma unroll
                for (int grp = 0; grp < 4; ++grp) {
                    const int rowl = 2*w + (grp >> 1);
                    const int cl = (grp & 1)*16 + m + q;
                    const int c7 = (cl + 4) & 7;     // == (j0-4+cl)&7 since j0%8==0
                    const char* pb = Xs + (size_t)(rowl*40 + cl)*128;
                    #pragma unroll
                    for (int pt = 0; pt < 2; ++pt)
                        xb[grp][pt] = *(const short8*)(pb + (((pt*4 + g) ^ c7) << 4));
                }
                #pragma unroll
                for (int grp = 0; grp < 4; ++grp) {
                    acc[grp][0] = __builtin_amdgcn_mfma_f32_16x16x32_bf16(wa[0][0], xb[grp][0], acc[grp][0], 0, 0, 0);
                    acc[grp][1] = __builtin_amdgcn_mfma_f32_16x16x32_bf16(wa[0][1], xb[grp][0], acc[grp][1], 0, 0, 0);
                    acc[grp][0] = __builtin_amdgcn_mfma_f32_16x16x32_bf16(wa[1][0], xb[grp][0], acc[grp][0], 0, 0, 0);
                    acc[grp][1] = __builtin_amdgcn_mfma_f32_16x16x32_bf16(wa[1][1], xb[grp][0], acc[grp][1], 0, 0, 0);
                    acc[grp][0] = __builtin_amdgcn_mfma_f32_16x16x32_bf16(wa[0][0], xb[grp][1], acc[grp][0], 0, 0, 0);
                    acc[grp][1] = __builtin_amdgcn_mfma_f32_16x16x32_bf16(wa[0][1], xb[grp][1], acc[grp][1], 0, 0, 0);
                }
            }
            if (half == 0) {   // swap in taps q=5..8
                __syncthreads();
                const char* wsrc = (const char*)Wd + (size_t)(p*9 + 5)*4096;
                for (int off = t*16; off < 4*4096; off += 4096)
                    *(uint4*)(Wl + off) = *(const uint4*)(wsrc + off);
                __syncthreads();
            }
        }
    }

    // ---- epilogue: C/D col = lane&15 = pixel, row = g*4+j = co
    const float am = (MODE >= 1) ? fabsf(miu[0]) : 0.f;
    float2 part = make_float2(0.f, 0.f);
    #pragma unroll
    for (int grp = 0; grp < 4; ++grp) {
        const int rowo = i0 + 2*w + (grp >> 1);
        const int colo = j0 + (grp & 1)*16 + m;
        const int pix = rowo*MM + colo;
        #pragma unroll
        for (int j = 0; j < 4; ++j) {
            const int co = g*4 + j;
            const size_t idx = (size_t)co*NPIX + pix;
            const float rr = acc[grp][0][j], ii = acc[grp][1][j];
            if (MODE == 0) {
                const float2 xc = x[idx];
                out[idx] = make_float2(rr - xc.x, ii - xc.y);
            } else if (MODE == 1) {
                const float2 tc = x[idx];
                const float2 pc = aux[idx];
                const float mv = mask8[idx] ? 1.f : 0.f;
                const float qr = rr - tc.x + (mv + am)*pc.x;
                const float qi = ii - tc.y + (mv + am)*pc.y;
                out[idx] = make_float2(qr, qi);
                part.x += qr*pc.x + qi*pc.y;
                part.y += qi*pc.x - qr*pc.y;
            } else {
                const float2 tc = x[idx];
                const float2 wc = aux[idx];
                const float mv = mask8[idx] ? 1.f : 0.f;
                const float kr_ = ks[(size_t)pix*32 + co];
                const float ki_ = ks[(size_t)pix*32 + co + 16];
                const float zr  = z[(size_t)pix*32 + co];
                const float zi  = z[(size_t)pix*32 + co + 16];
                const float pr = mv*kr_ + am*zr - (rr - tc.x) - (mv + am)*wc.x;
                const float pi = mv*ki_ + am*zi - (ii - tc.y) - (mv + am)*wc.y;
                out[idx]  = make_float2(pr, pi);
                out2[idx] = make_float2(pr, pi);
                part.x += pr*pr + pi*pi;
            }
        }
    }
    if (MODE >= 1) {
        __syncthreads();
        part = block_reduce2(part);
        if (t == 0) partials[bi] = part;
    }
}

__global__ void finalize_rr(const float2* __restrict__ partials, float* __restrict__ scal, int n) {
    float2 s = make_float2(0.f, 0.f);
    for (int i = threadIdx.x; i < n; i += blockDim.x) { s.x += partials[i].x; s.y += partials[i].y; }
    s = block_reduce2(s);
    if (threadIdx.x == 0) scal[0] = s.x;
}

__global__ void finalize_alpha(const float2* __restrict__ partials, float* __restrict__ scal, int n) {
    float2 s = make_float2(0.f, 0.f);
    for (int i = threadIdx.x; i < n; i += blockDim.x) { s.x += partials[i].x; s.y += partials[i].y; }
    s = block_reduce2(s);
    if (threadIdx.x == 0) {
        const float rr = scal[0];
        const float d = s.x*s.x + s.y*s.y;
        scal[1] =  rr * s.x / d;
        scal[2] = -rr * s.y / d;
    }
}

__global__ void update_br(float2* __restrict__ b, const float2* __restrict__ p,
                          float2* __restrict__ r, const float2* __restrict__ q,
                          const float* __restrict__ scal, float2* __restrict__ partials) {
    const float ar = scal[1], ai = scal[2];
    float2 s = make_float2(0.f, 0.f);
    for (int e = blockIdx.x*256 + threadIdx.x; e < N2; e += NRED*256) {
        const float2 pv = p[e], qv = q[e];
        float2 bv = b[e], rv = r[e];
        bv.x += ar*pv.x - ai*pv.y;
        bv.y += ar*pv.y + ai*pv.x;
        rv.x -= ar*qv.x - ai*qv.y;
        rv.y -= ar*qv.y + ai*qv.x;
        b[e] = bv; r[e] = rv;
        s.x += rv.x*rv.x + rv.y*rv.y;
    }
    s = block_reduce2(s);
    if (threadIdx.x == 0) partials[blockIdx.x] = s;
}

__global__ void finalize_beta(const float2* __restrict__ partials, float* __restrict__ scal) {
    float2 v = partials[threadIdx.x];
    v = block_reduce2(v);
    if (threadIdx.x == 0) {
        const float rn = v.x;
        scal[3] = rn / scal[0];
        scal[0] = rn;
    }
}

__global__ void update_p(float2* __restrict__ p, const float2* __restrict__ r,
                         const float* __restrict__ scal) {
    const float beta = scal[3];
    const int e = blockIdx.x*256 + threadIdx.x;
    if (e < N2) {
        const float2 pv = p[e], rv = r[e];
        p[e] = make_float2(rv.x + beta*pv.x, rv.y + beta*pv.y);
    }
}

__global__ void pack_out(const float2* __restrict__ b, float* __restrict__ out) {
    const int e = blockIdx.x*256 + threadIdx.x;
    if (e >= 32*NPIX) return;
    const int pix = e >> 5;
    const int cc  = e & 31;
    const float2 v = b[(size_t)(cc & 15)*NPIX + pix];
    out[e] = (cc < 16) ? v.x : v.y;
}

extern "C" void kernel_launch(void* const* d_in, const int* in_sizes, int n_in,
                              void* d_out, int out_size, void* d_ws, size_t ws_size,
                              hipStream_t stream) {
    const float* z    = (const float*)d_in[0];
    const float* ks   = (const float*)d_in[1];
    const float* kr   = (const float*)d_in[2];
    const float* ki   = (const float*)d_in[3];
    const float* prev = (const float*)d_in[5];
    const float* miu  = (const float*)d_in[6];
    float* out = (float*)d_out;

    char* w = (char*)d_ws;
    const size_t FB = (size_t)N2 * sizeof(float2);
    float2* wsf = (float2*)w; w += FB;    // b (in-place)
    float2* pf  = (float2*)w; w += FB;
    float2* rf  = (float2*)w; w += FB;
    float2* qf  = (float2*)w; w += FB;
    float2* tf  = (float2*)w; w += FB;
    u32* wbuf   = (u32*)w;   w += (size_t)2*324*256*sizeof(u32);   // 663552 B
    uint8_t* mask8 = (uint8_t*)w; w += (size_t)N2;
    w = (char*)(((uintptr_t)w + 255) & ~(uintptr_t)255);
    float2* partials = (float2*)w; w += (size_t)NCBLK * sizeof(float2);
    float*  scal     = (float*)w;

    const u32* wbF = wbuf;
    const u32* wbB = wbuf + (size_t)324*256;

    prep_weights<<<81, 256, 0, stream>>>(kr, ki, wbuf);
    prep_fields<<<576, 256, 0, stream>>>(ks, prev, wsf, mask8);

    conv9<0><<<NCBLK, 256, 0, stream>>>(wsf, wbF, tf, nullptr, nullptr, nullptr, nullptr, nullptr, nullptr, nullptr);
    conv9<2><<<NCBLK, 256, 0, stream>>>(tf, wbB, pf, rf, wsf, ks, z, mask8, miu, partials);
    finalize_rr<<<1, 256, 0, stream>>>(partials, scal, NCBLK);

    for (int it = 0; it < 10; ++it) {
        conv9<0><<<NCBLK, 256, 0, stream>>>(pf, wbF, tf, nullptr, nullptr, nullptr, nullptr, nullptr, nullptr, nullptr);
        conv9<1><<<NCBLK, 256, 0, stream>>>(tf, wbB, qf, nullptr, pf, nullptr, nullptr, mask8, miu, partials);
        finalize_alpha<<<1, 256, 0, stream>>>(partials, scal, NCBLK);
        update_br<<<NRED, 256, 0, stream>>>(wsf, pf, rf, qf, scal, partials);
        finalize_beta<<<1, NRED, 0, stream>>>(partials, scal);
        update_p<<<9216, 256, 0, stream>>>(pf, rf, scal);
    }

    pack_out<<<18432, 256, 0, stream>>>(wsf, out);
}

// Round 3
// 2561.460 us; speedup vs baseline: 2.7955x; 1.8601x over previous
//
#include <hip/hip_runtime.h>
#include <stdint.h>

// SPIRiT CG reconstruction. Convs via bf16 hi/lo-split MFMA (3 products:
// Wh*Xh + Wl*Xh + Wh*Xl), per-tap implicit GEMM: M=16 c_out, N=16 pixels,
// K=32 = 16 c_in x {re,im}. Fields are planar complex float2 f[c][384*384].
// Conv kernel: stage-once 24x24 slab in LDS, 81 taps barrier-free,
// weights global->register double-buffered.

#define MM 384
#define NPIX (MM*MM)          // 147456
#define N2 (16*NPIX)
#define NRED 512
#define NCBLK 576             // 24 x 24 tiles of 16x16 pixels

typedef __attribute__((ext_vector_type(8))) short short8;
typedef __attribute__((ext_vector_type(4))) float f32x4;
typedef unsigned int u32;

__device__ __forceinline__ float2 block_reduce2(float2 v) {
    #pragma unroll
    for (int off = 32; off > 0; off >>= 1) {
        v.x += __shfl_down(v.x, off);
        v.y += __shfl_down(v.y, off);
    }
    __shared__ float2 tmp[8];
    const int wid = threadIdx.x >> 6, lid = threadIdx.x & 63;
    if (lid == 0) tmp[wid] = v;
    __syncthreads();
    if (threadIdx.x == 0) {
        const int nw = blockDim.x >> 6;
        for (int i = 1; i < nw; ++i) { v.x += tmp[i].x; v.y += tmp[i].y; }
    }
    return v;
}

__device__ __forceinline__ void split_pair(float a, float b, u32& hw, u32& lw) {
    const u32 ua = __float_as_uint(a), ub = __float_as_uint(b);
    const u32 ha = ua & 0xFFFF0000u, hb = ub & 0xFFFF0000u;
    const float la = a - __uint_as_float(ha);
    const float lb = b - __uint_as_float(hb);
    hw = hb | (ha >> 16);
    lw = (__float_as_uint(lb) & 0xFFFF0000u) | (__float_as_uint(la) >> 16);
}

// Weight fragments: [dir][tap=p*9+q][pt(hi/lo)][hf][lane64][4 u32]
// A_half0[co][kc] = [Wr | -Wi], A_half1 = [Wi | Wr]; lane = co + 16*kgroup.
__global__ void prep_weights(const float* __restrict__ kr, const float* __restrict__ ki,
                             u32* __restrict__ wbuf) {
    const int e = blockIdx.x * 256 + threadIdx.x;
    if (e >= 20736) return;
    const int lane = e & 63;
    int r = e >> 6;
    const int hf = r & 1; r >>= 1;
    const int q = r % 9; r /= 9;
    const int p = r % 9; r /= 9;
    const int dir = r;
    const int co = lane & 15, g = lane >> 4;
    float vv[8];
    #pragma unroll
    for (int t = 0; t < 8; ++t) {
        const int kc = 8 * g + t;
        const int ci = kc & 15;
        const int isI = kc >> 4;
        int sidx;
        if (dir == 0) sidx = (q*9 + p)*256 + ci*16 + co;          // Wf[co,ci,p,q]=K[q,p,ci,co]
        else          sidx = ((8-q)*9 + (8-p))*256 + co*16 + ci;  // Wb = conj flip swap
        const float wr = kr[sidx];
        const float wi = (dir == 0) ? ki[sidx] : -ki[sidx];
        vv[t] = (hf == 0) ? (isI ? -wi : wr) : (isI ? wr : wi);
    }
    u32 hw[4], lw[4];
    #pragma unroll
    for (int t = 0; t < 4; ++t) split_pair(vv[2*t], vv[2*t+1], hw[t], lw[t]);
    const int b0 = dir*324 + (p*9 + q)*4 + hf;
    u32* o0 = wbuf + (size_t)b0*256 + lane*4;
    u32* o1 = o0 + 2*256;
    *(uint4*)o0 = make_uint4(hw[0], hw[1], hw[2], hw[3]);
    *(uint4*)o1 = make_uint4(lw[0], lw[1], lw[2], lw[3]);
}

__global__ void prep_fields(const float* __restrict__ ks, const float* __restrict__ prev,
                            float2* __restrict__ wsf, uint8_t* __restrict__ mask8) {
    const int pix = blockIdx.x * blockDim.x + threadIdx.x;
    if (pix >= NPIX) return;
    #pragma unroll
    for (int c = 0; c < 16; ++c) {
        const float krr = ks[(size_t)pix*32 + c];
        const float kii = ks[(size_t)pix*32 + c + 16];
        mask8[(size_t)c*NPIX + pix] = (krr != 0.f || kii != 0.f) ? 1 : 0;
        wsf[(size_t)c*NPIX + pix] = make_float2(prev[(size_t)pix*32 + c], prev[(size_t)pix*32 + c + 16]);
    }
}

// MODE 0: out = conv(x) - x
// MODE 1: out = conv(x) - x + (mask+am)*aux ; partial += out*conj(aux)
// MODE 2: out=out2 = mask*kk + am*z - (conv(x)-x) - (mask+am)*aux ; partial += |out|^2
template<int MODE>
__global__ __launch_bounds__(256)
void conv9(const float2* __restrict__ x, const u32* __restrict__ Wd,
           float2* __restrict__ out, float2* __restrict__ out2,
           const float2* __restrict__ aux, const float* __restrict__ ks,
           const float* __restrict__ z, const uint8_t* __restrict__ mask8,
           const float* __restrict__ miu, float2* __restrict__ partials)
{
    __shared__ __align__(16) char Xs[24*24*128];   // 73728 B -> 2 blocks/CU
    const int t = threadIdx.x;
    const int bi = blockIdx.x;
    const int i0 = (bi / 24) * 16;
    const int j0 = (bi % 24) * 16;
    const int w = t >> 6, lane = t & 63;
    const int m = lane & 15, g = lane >> 4;

    // ---- stage the full 24x24 slab once (rows i0-4..i0+19, cols j0-4..j0+19)
    for (int u = t; u < 24*24*2; u += 256) {
        const int col = u % 24;
        const int cih = (u / 24) & 1;
        const int row = u / 48;
        const int row_g = i0 - 4 + row;
        const int col_g = j0 - 4 + col;
        const bool valid = ((unsigned)row_g < MM) && ((unsigned)col_g < MM);
        float2 v[8];
        const float2* src = x + (size_t)(cih*8)*NPIX + (size_t)row_g*MM + col_g;
        #pragma unroll
        for (int e = 0; e < 8; ++e)
            v[e] = valid ? src[(size_t)e*NPIX] : make_float2(0.f, 0.f);
        u32 reh[4], rel[4], imh[4], iml[4];
        #pragma unroll
        for (int k2 = 0; k2 < 4; ++k2) {
            split_pair(v[2*k2].x, v[2*k2+1].x, reh[k2], rel[k2]);
            split_pair(v[2*k2].y, v[2*k2+1].y, imh[k2], iml[k2]);
        }
        const int c7 = (col + 4) & 7;    // == col_g & 7 (j0 % 8 == 0)
        char* pb = Xs + (size_t)(row*24 + col)*128;
        *(uint4*)(pb + (((0 + cih) ^ c7) << 4)) = make_uint4(reh[0], reh[1], reh[2], reh[3]);
        *(uint4*)(pb + (((2 + cih) ^ c7) << 4)) = make_uint4(imh[0], imh[1], imh[2], imh[3]);
        *(uint4*)(pb + (((4 + cih) ^ c7) << 4)) = make_uint4(rel[0], rel[1], rel[2], rel[3]);
        *(uint4*)(pb + (((6 + cih) ^ c7) << 4)) = make_uint4(iml[0], iml[1], iml[2], iml[3]);
    }
    __syncthreads();

    f32x4 acc[4][2];
    #pragma unroll
    for (int a = 0; a < 4; ++a)
        #pragma unroll
        for (int h = 0; h < 2; ++h) acc[a][h] = (f32x4){0.f, 0.f, 0.f, 0.f};

    // ---- 81 taps, weights double-buffered in registers (named bufs, no runtime idx)
    const char* wbase = (const char*)Wd + (lane << 4);
    short8 waA[2][2], waB[2][2];
    int pc = 0, qc = 0;

    #define LOADW(DST, TAP) { const char* s_ = wbase + (size_t)(TAP)*4096;        \
        DST[0][0] = *(const short8*)(s_);                                          \
        DST[0][1] = *(const short8*)(s_ + 1024);                                   \
        DST[1][0] = *(const short8*)(s_ + 2048);                                   \
        DST[1][1] = *(const short8*)(s_ + 3072); }

    #define COMPUTE(WR) {                                                          \
        const int cl = m + qc;                                                     \
        const int c7 = (cl + 4) & 7;                                               \
        const char* pbase = Xs + (size_t)(((4*w + pc))*24 + cl)*128;               \
        short8 xb0[4], xb1[4];                                                     \
        _Pragma("unroll")                                                          \
        for (int grp = 0; grp < 4; ++grp) {                                        \
            const char* pb = pbase + grp*(24*128);                                 \
            xb0[grp] = *(const short8*)(pb + ((g ^ c7) << 4));                     \
            xb1[grp] = *(const short8*)(pb + (((4 + g) ^ c7) << 4));               \
        }                                                                          \
        _Pragma("unroll")                                                          \
        for (int grp = 0; grp < 4; ++grp) {                                        \
            acc[grp][0] = __builtin_amdgcn_mfma_f32_16x16x32_bf16(WR[0][0], xb0[grp], acc[grp][0], 0, 0, 0); \
            acc[grp][1] = __builtin_amdgcn_mfma_f32_16x16x32_bf16(WR[0][1], xb0[grp], acc[grp][1], 0, 0, 0); \
            acc[grp][0] = __builtin_amdgcn_mfma_f32_16x16x32_bf16(WR[1][0], xb0[grp], acc[grp][0], 0, 0, 0); \
            acc[grp][1] = __builtin_amdgcn_mfma_f32_16x16x32_bf16(WR[1][1], xb0[grp], acc[grp][1], 0, 0, 0); \
            acc[grp][0] = __builtin_amdgcn_mfma_f32_16x16x32_bf16(WR[0][0], xb1[grp], acc[grp][0], 0, 0, 0); \
            acc[grp][1] = __builtin_amdgcn_mfma_f32_16x16x32_bf16(WR[0][1], xb1[grp], acc[grp][1], 0, 0, 0); \
        }                                                                          \
        if (++qc == 9) { qc = 0; ++pc; } }

    LOADW(waA, 0);
    for (int tap = 0; tap < 80; tap += 2) {
        LOADW(waB, tap + 1);
        COMPUTE(waA);
        LOADW(waA, tap + 2);
        COMPUTE(waB);
    }
    COMPUTE(waA);   // tap 80

    #undef LOADW
    #undef COMPUTE

    // ---- epilogue: C/D col = lane&15 = pixel, row = g*4+j = co
    const float am = (MODE >= 1) ? fabsf(miu[0]) : 0.f;
    float2 part = make_float2(0.f, 0.f);
    #pragma unroll
    for (int grp = 0; grp < 4; ++grp) {
        const int rowo = i0 + 4*w + grp;
        const int colo = j0 + m;
        const int pix = rowo*MM + colo;
        #pragma unroll
        for (int j = 0; j < 4; ++j) {
            const int co = g*4 + j;
            const size_t idx = (size_t)co*NPIX + pix;
            const float rr = acc[grp][0][j], ii = acc[grp][1][j];
            if (MODE == 0) {
                const float2 xc = x[idx];
                out[idx] = make_float2(rr - xc.x, ii - xc.y);
            } else if (MODE == 1) {
                const float2 tc = x[idx];
                const float2 pc = aux[idx];
                const float mv = mask8[idx] ? 1.f : 0.f;
                const float qr = rr - tc.x + (mv + am)*pc.x;
                const float qi = ii - tc.y + (mv + am)*pc.y;
                out[idx] = make_float2(qr, qi);
                part.x += qr*pc.x + qi*pc.y;
                part.y += qi*pc.x - qr*pc.y;
            } else {
                const float2 tc = x[idx];
                const float2 wc = aux[idx];
                const float mv = mask8[idx] ? 1.f : 0.f;
                const float kr_ = ks[(size_t)pix*32 + co];
                const float ki_ = ks[(size_t)pix*32 + co + 16];
                const float zr  = z[(size_t)pix*32 + co];
                const float zi  = z[(size_t)pix*32 + co + 16];
                const float pr = mv*kr_ + am*zr - (rr - tc.x) - (mv + am)*wc.x;
                const float pi = mv*ki_ + am*zi - (ii - tc.y) - (mv + am)*wc.y;
                out[idx]  = make_float2(pr, pi);
                out2[idx] = make_float2(pr, pi);
                part.x += pr*pr + pi*pi;
            }
        }
    }
    if (MODE >= 1) {
        __syncthreads();
        part = block_reduce2(part);
        if (t == 0) partials[bi] = part;
    }
}

__global__ void finalize_rr(const float2* __restrict__ partials, float* __restrict__ scal, int n) {
    float2 s = make_float2(0.f, 0.f);
    for (int i = threadIdx.x; i < n; i += blockDim.x) { s.x += partials[i].x; s.y += partials[i].y; }
    s = block_reduce2(s);
    if (threadIdx.x == 0) scal[0] = s.x;
}

__global__ void finalize_alpha(const float2* __restrict__ partials, float* __restrict__ scal, int n) {
    float2 s = make_float2(0.f, 0.f);
    for (int i = threadIdx.x; i < n; i += blockDim.x) { s.x += partials[i].x; s.y += partials[i].y; }
    s = block_reduce2(s);
    if (threadIdx.x == 0) {
        const float rr = scal[0];
        const float d = s.x*s.x + s.y*s.y;
        scal[1] =  rr * s.x / d;
        scal[2] = -rr * s.y / d;
    }
}

__global__ void update_br(float2* __restrict__ b, const float2* __restrict__ p,
                          float2* __restrict__ r, const float2* __restrict__ q,
                          const float* __restrict__ scal, float2* __restrict__ partials) {
    const float ar = scal[1], ai = scal[2];
    float2 s = make_float2(0.f, 0.f);
    for (int e = blockIdx.x*256 + threadIdx.x; e < N2; e += NRED*256) {
        const float2 pv = p[e], qv = q[e];
        float2 bv = b[e], rv = r[e];
        bv.x += ar*pv.x - ai*pv.y;
        bv.y += ar*pv.y + ai*pv.x;
        rv.x -= ar*qv.x - ai*qv.y;
        rv.y -= ar*qv.y + ai*qv.x;
        b[e] = bv; r[e] = rv;
        s.x += rv.x*rv.x + rv.y*rv.y;
    }
    s = block_reduce2(s);
    if (threadIdx.x == 0) partials[blockIdx.x] = s;
}

__global__ void finalize_beta(const float2* __restrict__ partials, float* __restrict__ scal) {
    float2 v = partials[threadIdx.x];
    v = block_reduce2(v);
    if (threadIdx.x == 0) {
        const float rn = v.x;
        scal[3] = rn / scal[0];
        scal[0] = rn;
    }
}

__global__ void update_p(float2* __restrict__ p, const float2* __restrict__ r,
                         const float* __restrict__ scal) {
    const float beta = scal[3];
    const int e = blockIdx.x*256 + threadIdx.x;
    if (e < N2) {
        const float2 pv = p[e], rv = r[e];
        p[e] = make_float2(rv.x + beta*pv.x, rv.y + beta*pv.y);
    }
}

__global__ void pack_out(const float2* __restrict__ b, float* __restrict__ out) {
    const int e = blockIdx.x*256 + threadIdx.x;
    if (e >= 32*NPIX) return;
    const int pix = e >> 5;
    const int cc  = e & 31;
    const float2 v = b[(size_t)(cc & 15)*NPIX + pix];
    out[e] = (cc < 16) ? v.x : v.y;
}

extern "C" void kernel_launch(void* const* d_in, const int* in_sizes, int n_in,
                              void* d_out, int out_size, void* d_ws, size_t ws_size,
                              hipStream_t stream) {
    const float* z    = (const float*)d_in[0];
    const float* ks   = (const float*)d_in[1];
    const float* kr   = (const float*)d_in[2];
    const float* ki   = (const float*)d_in[3];
    const float* prev = (const float*)d_in[5];
    const float* miu  = (const float*)d_in[6];
    float* out = (float*)d_out;

    char* w = (char*)d_ws;
    const size_t FB = (size_t)N2 * sizeof(float2);
    float2* wsf = (float2*)w; w += FB;    // b (in-place)
    float2* pf  = (float2*)w; w += FB;
    float2* rf  = (float2*)w; w += FB;
    float2* qf  = (float2*)w; w += FB;
    float2* tf  = (float2*)w; w += FB;
    u32* wbuf   = (u32*)w;   w += (size_t)2*324*256*sizeof(u32);
    uint8_t* mask8 = (uint8_t*)w; w += (size_t)N2;
    w = (char*)(((uintptr_t)w + 255) & ~(uintptr_t)255);
    float2* partials = (float2*)w; w += (size_t)NCBLK * sizeof(float2);
    float*  scal     = (float*)w;

    const u32* wbF = wbuf;
    const u32* wbB = wbuf + (size_t)324*256;

    prep_weights<<<81, 256, 0, stream>>>(kr, ki, wbuf);
    prep_fields<<<576, 256, 0, stream>>>(ks, prev, wsf, mask8);

    conv9<0><<<NCBLK, 256, 0, stream>>>(wsf, wbF, tf, nullptr, nullptr, nullptr, nullptr, nullptr, nullptr, nullptr);
    conv9<2><<<NCBLK, 256, 0, stream>>>(tf, wbB, pf, rf, wsf, ks, z, mask8, miu, partials);
    finalize_rr<<<1, 256, 0, stream>>>(partials, scal, NCBLK);

    for (int it = 0; it < 10; ++it) {
        conv9<0><<<NCBLK, 256, 0, stream>>>(pf, wbF, tf, nullptr, nullptr, nullptr, nullptr, nullptr, nullptr, nullptr);
        conv9<1><<<NCBLK, 256, 0, stream>>>(tf, wbB, qf, nullptr, pf, nullptr, nullptr, mask8, miu, partials);
        finalize_alpha<<<1, 256, 0, stream>>>(partials, scal, NCBLK);
        update_br<<<NRED, 256, 0, stream>>>(wsf, pf, rf, qf, scal, partials);
        finalize_beta<<<1, NRED, 0, stream>>>(partials, scal);
        update_p<<<9216, 256, 0, stream>>>(pf, rf, scal);
    }

    pack_out<<<18432, 256, 0, stream>>>(wsf, out);
}

// Round 4
// 2401.544 us; speedup vs baseline: 2.9816x; 1.0666x over previous
//
#include <hip/hip_runtime.h>
#include <stdint.h>

// SPIRiT CG reconstruction. Convs via bf16 hi/lo-split MFMA (3 products:
// Wh*Xh + Wl*Xh + Wh*Xl), per-tap implicit GEMM: M=16 c_out, N=16 pixels,
// K=32 = 16 c_in x {re,im}. Fields are planar complex float2 f[c][384*384].
// Conv kernel: 512 threads (8 waves) per 16x16 tile -> 4 waves/SIMD,
// stage-once 24x24 slab in LDS, 81 taps barrier-free, weights
// global->register double-buffered.

#define MM 384
#define NPIX (MM*MM)          // 147456
#define N2 (16*NPIX)
#define NRED 512
#define NCBLK 576             // 24 x 24 tiles of 16x16 pixels

typedef __attribute__((ext_vector_type(8))) short short8;
typedef __attribute__((ext_vector_type(4))) float f32x4;
typedef unsigned int u32;

__device__ __forceinline__ float2 block_reduce2(float2 v) {
    #pragma unroll
    for (int off = 32; off > 0; off >>= 1) {
        v.x += __shfl_down(v.x, off);
        v.y += __shfl_down(v.y, off);
    }
    __shared__ float2 tmp[8];
    const int wid = threadIdx.x >> 6, lid = threadIdx.x & 63;
    if (lid == 0) tmp[wid] = v;
    __syncthreads();
    if (threadIdx.x == 0) {
        const int nw = blockDim.x >> 6;
        for (int i = 1; i < nw; ++i) { v.x += tmp[i].x; v.y += tmp[i].y; }
    }
    return v;
}

__device__ __forceinline__ void split_pair(float a, float b, u32& hw, u32& lw) {
    const u32 ua = __float_as_uint(a), ub = __float_as_uint(b);
    const u32 ha = ua & 0xFFFF0000u, hb = ub & 0xFFFF0000u;
    const float la = a - __uint_as_float(ha);
    const float lb = b - __uint_as_float(hb);
    hw = hb | (ha >> 16);
    lw = (__float_as_uint(lb) & 0xFFFF0000u) | (__float_as_uint(la) >> 16);
}

// Weight fragments: [dir][tap=p*9+q][pt(hi/lo)][hf][lane64][4 u32]
// A_half0[co][kc] = [Wr | -Wi], A_half1 = [Wi | Wr]; lane = co + 16*kgroup.
__global__ void prep_weights(const float* __restrict__ kr, const float* __restrict__ ki,
                             u32* __restrict__ wbuf) {
    const int e = blockIdx.x * 256 + threadIdx.x;
    if (e >= 20736) return;
    const int lane = e & 63;
    int r = e >> 6;
    const int hf = r & 1; r >>= 1;
    const int q = r % 9; r /= 9;
    const int p = r % 9; r /= 9;
    const int dir = r;
    const int co = lane & 15, g = lane >> 4;
    float vv[8];
    #pragma unroll
    for (int t = 0; t < 8; ++t) {
        const int kc = 8 * g + t;
        const int ci = kc & 15;
        const int isI = kc >> 4;
        int sidx;
        if (dir == 0) sidx = (q*9 + p)*256 + ci*16 + co;          // Wf[co,ci,p,q]=K[q,p,ci,co]
        else          sidx = ((8-q)*9 + (8-p))*256 + co*16 + ci;  // Wb = conj flip swap
        const float wr = kr[sidx];
        const float wi = (dir == 0) ? ki[sidx] : -ki[sidx];
        vv[t] = (hf == 0) ? (isI ? -wi : wr) : (isI ? wr : wi);
    }
    u32 hw[4], lw[4];
    #pragma unroll
    for (int t = 0; t < 4; ++t) split_pair(vv[2*t], vv[2*t+1], hw[t], lw[t]);
    const int b0 = dir*324 + (p*9 + q)*4 + hf;
    u32* o0 = wbuf + (size_t)b0*256 + lane*4;
    u32* o1 = o0 + 2*256;
    *(uint4*)o0 = make_uint4(hw[0], hw[1], hw[2], hw[3]);
    *(uint4*)o1 = make_uint4(lw[0], lw[1], lw[2], lw[3]);
}

__global__ void prep_fields(const float* __restrict__ ks, const float* __restrict__ prev,
                            float2* __restrict__ wsf, uint8_t* __restrict__ mask8) {
    const int pix = blockIdx.x * blockDim.x + threadIdx.x;
    if (pix >= NPIX) return;
    #pragma unroll
    for (int c = 0; c < 16; ++c) {
        const float krr = ks[(size_t)pix*32 + c];
        const float kii = ks[(size_t)pix*32 + c + 16];
        mask8[(size_t)c*NPIX + pix] = (krr != 0.f || kii != 0.f) ? 1 : 0;
        wsf[(size_t)c*NPIX + pix] = make_float2(prev[(size_t)pix*32 + c], prev[(size_t)pix*32 + c + 16]);
    }
}

// MODE 0: out = conv(x) - x
// MODE 1: out = conv(x) - x + (mask+am)*aux ; partial += out*conj(aux)
// MODE 2: out=out2 = mask*kk + am*z - (conv(x)-x) - (mask+am)*aux ; partial += |out|^2
template<int MODE>
__global__ __launch_bounds__(512)
void conv9(const float2* __restrict__ x, const u32* __restrict__ Wd,
           float2* __restrict__ out, float2* __restrict__ out2,
           const float2* __restrict__ aux, const float* __restrict__ ks,
           const float* __restrict__ z, const uint8_t* __restrict__ mask8,
           const float* __restrict__ miu, float2* __restrict__ partials)
{
    __shared__ __align__(16) char Xs[24*24*128];   // 73728 B -> 2 blocks/CU
    const int t = threadIdx.x;
    const int bi = blockIdx.x;
    const int i0 = (bi / 24) * 16;
    const int j0 = (bi % 24) * 16;
    const int w = t >> 6, lane = t & 63;
    const int m = lane & 15, g = lane >> 4;

    // ---- stage the full 24x24 slab once (rows i0-4..i0+19, cols j0-4..j0+19)
    for (int u = t; u < 24*24*2; u += 512) {
        const int col = u % 24;
        const int cih = (u / 24) & 1;
        const int row = u / 48;
        const int row_g = i0 - 4 + row;
        const int col_g = j0 - 4 + col;
        const bool valid = ((unsigned)row_g < MM) && ((unsigned)col_g < MM);
        float2 v[8];
        const float2* src = x + (size_t)(cih*8)*NPIX + (size_t)row_g*MM + col_g;
        #pragma unroll
        for (int e = 0; e < 8; ++e)
            v[e] = valid ? src[(size_t)e*NPIX] : make_float2(0.f, 0.f);
        u32 reh[4], rel[4], imh[4], iml[4];
        #pragma unroll
        for (int k2 = 0; k2 < 4; ++k2) {
            split_pair(v[2*k2].x, v[2*k2+1].x, reh[k2], rel[k2]);
            split_pair(v[2*k2].y, v[2*k2+1].y, imh[k2], iml[k2]);
        }
        const int c7 = (col + 4) & 7;    // == col_g & 7 (j0 % 8 == 0)
        char* pb = Xs + (size_t)(row*24 + col)*128;
        *(uint4*)(pb + (((0 + cih) ^ c7) << 4)) = make_uint4(reh[0], reh[1], reh[2], reh[3]);
        *(uint4*)(pb + (((2 + cih) ^ c7) << 4)) = make_uint4(imh[0], imh[1], imh[2], imh[3]);
        *(uint4*)(pb + (((4 + cih) ^ c7) << 4)) = make_uint4(rel[0], rel[1], rel[2], rel[3]);
        *(uint4*)(pb + (((6 + cih) ^ c7) << 4)) = make_uint4(iml[0], iml[1], iml[2], iml[3]);
    }
    __syncthreads();

    f32x4 acc[2][2];
    #pragma unroll
    for (int a = 0; a < 2; ++a)
        #pragma unroll
        for (int h = 0; h < 2; ++h) acc[a][h] = (f32x4){0.f, 0.f, 0.f, 0.f};

    // ---- 81 taps, weights double-buffered in registers (named bufs, no runtime idx)
    const char* wbase = (const char*)Wd + (lane << 4);
    short8 waA[2][2], waB[2][2];
    int pc = 0, qc = 0;

    #define LOADW(DST, TAP) { const char* s_ = wbase + (size_t)(TAP)*4096;        \
        DST[0][0] = *(const short8*)(s_);                                          \
        DST[0][1] = *(const short8*)(s_ + 1024);                                   \
        DST[1][0] = *(const short8*)(s_ + 2048);                                   \
        DST[1][1] = *(const short8*)(s_ + 3072); }

    #define COMPUTE(WR) {                                                          \
        const int cl = m + qc;                                                     \
        const int c7 = (cl + 4) & 7;                                               \
        const char* pbase = Xs + (size_t)(((2*w + pc))*24 + cl)*128;               \
        short8 xb0[2], xb1[2];                                                     \
        _Pragma("unroll")                                                          \
        for (int grp = 0; grp < 2; ++grp) {                                        \
            const char* pb = pbase + grp*(24*128);                                 \
            xb0[grp] = *(const short8*)(pb + ((g ^ c7) << 4));                     \
            xb1[grp] = *(const short8*)(pb + (((4 + g) ^ c7) << 4));               \
        }                                                                          \
        _Pragma("unroll")                                                          \
        for (int grp = 0; grp < 2; ++grp) {                                        \
            acc[grp][0] = __builtin_amdgcn_mfma_f32_16x16x32_bf16(WR[0][0], xb0[grp], acc[grp][0], 0, 0, 0); \
            acc[grp][1] = __builtin_amdgcn_mfma_f32_16x16x32_bf16(WR[0][1], xb0[grp], acc[grp][1], 0, 0, 0); \
            acc[grp][0] = __builtin_amdgcn_mfma_f32_16x16x32_bf16(WR[1][0], xb0[grp], acc[grp][0], 0, 0, 0); \
            acc[grp][1] = __builtin_amdgcn_mfma_f32_16x16x32_bf16(WR[1][1], xb0[grp], acc[grp][1], 0, 0, 0); \
            acc[grp][0] = __builtin_amdgcn_mfma_f32_16x16x32_bf16(WR[0][0], xb1[grp], acc[grp][0], 0, 0, 0); \
            acc[grp][1] = __builtin_amdgcn_mfma_f32_16x16x32_bf16(WR[0][1], xb1[grp], acc[grp][1], 0, 0, 0); \
        }                                                                          \
        if (++qc == 9) { qc = 0; ++pc; } }

    LOADW(waA, 0);
    for (int tap = 0; tap < 80; tap += 2) {
        LOADW(waB, tap + 1);
        COMPUTE(waA);
        LOADW(waA, tap + 2);
        COMPUTE(waB);
    }
    COMPUTE(waA);   // tap 80

    #undef LOADW
    #undef COMPUTE

    // ---- epilogue: C/D col = lane&15 = pixel, row = g*4+j = co
    const float am = (MODE >= 1) ? fabsf(miu[0]) : 0.f;
    float2 part = make_float2(0.f, 0.f);
    #pragma unroll
    for (int grp = 0; grp < 2; ++grp) {
        const int rowo = i0 + 2*w + grp;
        const int colo = j0 + m;
        const int pix = rowo*MM + colo;
        #pragma unroll
        for (int j = 0; j < 4; ++j) {
            const int co = g*4 + j;
            const size_t idx = (size_t)co*NPIX + pix;
            const float rr = acc[grp][0][j], ii = acc[grp][1][j];
            if (MODE == 0) {
                const float2 xc = x[idx];
                out[idx] = make_float2(rr - xc.x, ii - xc.y);
            } else if (MODE == 1) {
                const float2 tc = x[idx];
                const float2 pc = aux[idx];
                const float mv = mask8[idx] ? 1.f : 0.f;
                const float qr = rr - tc.x + (mv + am)*pc.x;
                const float qi = ii - tc.y + (mv + am)*pc.y;
                out[idx] = make_float2(qr, qi);
                part.x += qr*pc.x + qi*pc.y;
                part.y += qi*pc.x - qr*pc.y;
            } else {
                const float2 tc = x[idx];
                const float2 wc = aux[idx];
                const float mv = mask8[idx] ? 1.f : 0.f;
                const float kr_ = ks[(size_t)pix*32 + co];
                const float ki_ = ks[(size_t)pix*32 + co + 16];
                const float zr  = z[(size_t)pix*32 + co];
                const float zi  = z[(size_t)pix*32 + co + 16];
                const float pr = mv*kr_ + am*zr - (rr - tc.x) - (mv + am)*wc.x;
                const float pi = mv*ki_ + am*zi - (ii - tc.y) - (mv + am)*wc.y;
                out[idx]  = make_float2(pr, pi);
                out2[idx] = make_float2(pr, pi);
                part.x += pr*pr + pi*pi;
            }
        }
    }
    if (MODE >= 1) {
        __syncthreads();
        part = block_reduce2(part);
        if (t == 0) partials[bi] = part;
    }
}

__global__ void finalize_rr(const float2* __restrict__ partials, float* __restrict__ scal, int n) {
    float2 s = make_float2(0.f, 0.f);
    for (int i = threadIdx.x; i < n; i += blockDim.x) { s.x += partials[i].x; s.y += partials[i].y; }
    s = block_reduce2(s);
    if (threadIdx.x == 0) scal[0] = s.x;
}

__global__ void finalize_alpha(const float2* __restrict__ partials, float* __restrict__ scal, int n) {
    float2 s = make_float2(0.f, 0.f);
    for (int i = threadIdx.x; i < n; i += blockDim.x) { s.x += partials[i].x; s.y += partials[i].y; }
    s = block_reduce2(s);
    if (threadIdx.x == 0) {
        const float rr = scal[0];
        const float d = s.x*s.x + s.y*s.y;
        scal[1] =  rr * s.x / d;
        scal[2] = -rr * s.y / d;
    }
}

__global__ void update_br(float2* __restrict__ b, const float2* __restrict__ p,
                          float2* __restrict__ r, const float2* __restrict__ q,
                          const float* __restrict__ scal, float2* __restrict__ partials) {
    const float ar = scal[1], ai = scal[2];
    float2 s = make_float2(0.f, 0.f);
    for (int e = blockIdx.x*256 + threadIdx.x; e < N2; e += NRED*256) {
        const float2 pv = p[e], qv = q[e];
        float2 bv = b[e], rv = r[e];
        bv.x += ar*pv.x - ai*pv.y;
        bv.y += ar*pv.y + ai*pv.x;
        rv.x -= ar*qv.x - ai*qv.y;
        rv.y -= ar*qv.y + ai*qv.x;
        b[e] = bv; r[e] = rv;
        s.x += rv.x*rv.x + rv.y*rv.y;
    }
    s = block_reduce2(s);
    if (threadIdx.x == 0) partials[blockIdx.x] = s;
}

__global__ void finalize_beta(const float2* __restrict__ partials, float* __restrict__ scal) {
    float2 v = partials[threadIdx.x];
    v = block_reduce2(v);
    if (threadIdx.x == 0) {
        const float rn = v.x;
        scal[3] = rn / scal[0];
        scal[0] = rn;
    }
}

__global__ void update_p(float2* __restrict__ p, const float2* __restrict__ r,
                         const float* __restrict__ scal) {
    const float beta = scal[3];
    const int e = blockIdx.x*256 + threadIdx.x;
    if (e < N2) {
        const float2 pv = p[e], rv = r[e];
        p[e] = make_float2(rv.x + beta*pv.x, rv.y + beta*pv.y);
    }
}

__global__ void pack_out(const float2* __restrict__ b, float* __restrict__ out) {
    const int e = blockIdx.x*256 + threadIdx.x;
    if (e >= 32*NPIX) return;
    const int pix = e >> 5;
    const int cc  = e & 31;
    const float2 v = b[(size_t)(cc & 15)*NPIX + pix];
    out[e] = (cc < 16) ? v.x : v.y;
}

extern "C" void kernel_launch(void* const* d_in, const int* in_sizes, int n_in,
                              void* d_out, int out_size, void* d_ws, size_t ws_size,
                              hipStream_t stream) {
    const float* z    = (const float*)d_in[0];
    const float* ks   = (const float*)d_in[1];
    const float* kr   = (const float*)d_in[2];
    const float* ki   = (const float*)d_in[3];
    const float* prev = (const float*)d_in[5];
    const float* miu  = (const float*)d_in[6];
    float* out = (float*)d_out;

    char* w = (char*)d_ws;
    const size_t FB = (size_t)N2 * sizeof(float2);
    float2* wsf = (float2*)w; w += FB;    // b (in-place)
    float2* pf  = (float2*)w; w += FB;
    float2* rf  = (float2*)w; w += FB;
    float2* qf  = (float2*)w; w += FB;
    float2* tf  = (float2*)w; w += FB;
    u32* wbuf   = (u32*)w;   w += (size_t)2*324*256*sizeof(u32);
    uint8_t* mask8 = (uint8_t*)w; w += (size_t)N2;
    w = (char*)(((uintptr_t)w + 255) & ~(uintptr_t)255);
    float2* partials = (float2*)w; w += (size_t)NCBLK * sizeof(float2);
    float*  scal     = (float*)w;

    const u32* wbF = wbuf;
    const u32* wbB = wbuf + (size_t)324*256;

    prep_weights<<<81, 256, 0, stream>>>(kr, ki, wbuf);
    prep_fields<<<576, 256, 0, stream>>>(ks, prev, wsf, mask8);

    conv9<0><<<NCBLK, 512, 0, stream>>>(wsf, wbF, tf, nullptr, nullptr, nullptr, nullptr, nullptr, nullptr, nullptr);
    conv9<2><<<NCBLK, 512, 0, stream>>>(tf, wbB, pf, rf, wsf, ks, z, mask8, miu, partials);
    finalize_rr<<<1, 256, 0, stream>>>(partials, scal, NCBLK);

    for (int it = 0; it < 10; ++it) {
        conv9<0><<<NCBLK, 512, 0, stream>>>(pf, wbF, tf, nullptr, nullptr, nullptr, nullptr, nullptr, nullptr, nullptr);
        conv9<1><<<NCBLK, 512, 0, stream>>>(tf, wbB, qf, nullptr, pf, nullptr, nullptr, mask8, miu, partials);
        finalize_alpha<<<1, 256, 0, stream>>>(partials, scal, NCBLK);
        update_br<<<NRED, 256, 0, stream>>>(wsf, pf, rf, qf, scal, partials);
        finalize_beta<<<1, NRED, 0, stream>>>(partials, scal);
        update_p<<<9216, 256, 0, stream>>>(pf, rf, scal);
    }

    pack_out<<<18432, 256, 0, stream>>>(wsf, out);
}

// Round 5
// 2295.756 us; speedup vs baseline: 3.1190x; 1.0461x over previous
//
#include <hip/hip_runtime.h>
#include <stdint.h>

// SPIRiT CG reconstruction. Convs via bf16 hi/lo-split MFMA (3 products:
// Wh*Xh + Wl*Xh + Wh*Xl), per-tap implicit GEMM: M=16 c_out, N=16 pixels,
// K=32 = 16 c_in x {re,im}. Fields are planar complex float2 f[c][384*384].
// Conv kernel: 512 threads (8 waves) per 16x16 tile, stage-once 24x24 slab,
// 81 taps barrier-free. Deep pipelining: 3-tap weight register ring
// (global->reg) + 1-tap X-fragment register prefetch (LDS->reg).

#define MM 384
#define NPIX (MM*MM)          // 147456
#define N2 (16*NPIX)
#define NRED 512
#define NCBLK 576             // 24 x 24 tiles of 16x16 pixels

typedef __attribute__((ext_vector_type(8))) short short8;
typedef __attribute__((ext_vector_type(4))) float f32x4;
typedef unsigned int u32;

__device__ __forceinline__ float2 block_reduce2(float2 v) {
    #pragma unroll
    for (int off = 32; off > 0; off >>= 1) {
        v.x += __shfl_down(v.x, off);
        v.y += __shfl_down(v.y, off);
    }
    __shared__ float2 tmp[8];
    const int wid = threadIdx.x >> 6, lid = threadIdx.x & 63;
    if (lid == 0) tmp[wid] = v;
    __syncthreads();
    if (threadIdx.x == 0) {
        const int nw = blockDim.x >> 6;
        for (int i = 1; i < nw; ++i) { v.x += tmp[i].x; v.y += tmp[i].y; }
    }
    return v;
}

__device__ __forceinline__ void split_pair(float a, float b, u32& hw, u32& lw) {
    const u32 ua = __float_as_uint(a), ub = __float_as_uint(b);
    const u32 ha = ua & 0xFFFF0000u, hb = ub & 0xFFFF0000u;
    const float la = a - __uint_as_float(ha);
    const float lb = b - __uint_as_float(hb);
    hw = hb | (ha >> 16);
    lw = (__float_as_uint(lb) & 0xFFFF0000u) | (__float_as_uint(la) >> 16);
}

// Weight fragments: [dir][tap=p*9+q][pt(hi/lo)][hf][lane64][4 u32]
// A_half0[co][kc] = [Wr | -Wi], A_half1 = [Wi | Wr]; lane = co + 16*kgroup.
__global__ void prep_weights(const float* __restrict__ kr, const float* __restrict__ ki,
                             u32* __restrict__ wbuf) {
    const int e = blockIdx.x * 256 + threadIdx.x;
    if (e >= 20736) return;
    const int lane = e & 63;
    int r = e >> 6;
    const int hf = r & 1; r >>= 1;
    const int q = r % 9; r /= 9;
    const int p = r % 9; r /= 9;
    const int dir = r;
    const int co = lane & 15, g = lane >> 4;
    float vv[8];
    #pragma unroll
    for (int t = 0; t < 8; ++t) {
        const int kc = 8 * g + t;
        const int ci = kc & 15;
        const int isI = kc >> 4;
        int sidx;
        if (dir == 0) sidx = (q*9 + p)*256 + ci*16 + co;          // Wf[co,ci,p,q]=K[q,p,ci,co]
        else          sidx = ((8-q)*9 + (8-p))*256 + co*16 + ci;  // Wb = conj flip swap
        const float wr = kr[sidx];
        const float wi = (dir == 0) ? ki[sidx] : -ki[sidx];
        vv[t] = (hf == 0) ? (isI ? -wi : wr) : (isI ? wr : wi);
    }
    u32 hw[4], lw[4];
    #pragma unroll
    for (int t = 0; t < 4; ++t) split_pair(vv[2*t], vv[2*t+1], hw[t], lw[t]);
    const int b0 = dir*324 + (p*9 + q)*4 + hf;
    u32* o0 = wbuf + (size_t)b0*256 + lane*4;
    u32* o1 = o0 + 2*256;
    *(uint4*)o0 = make_uint4(hw[0], hw[1], hw[2], hw[3]);
    *(uint4*)o1 = make_uint4(lw[0], lw[1], lw[2], lw[3]);
}

__global__ void prep_fields(const float* __restrict__ ks, const float* __restrict__ prev,
                            float2* __restrict__ wsf, uint8_t* __restrict__ mask8) {
    const int pix = blockIdx.x * blockDim.x + threadIdx.x;
    if (pix >= NPIX) return;
    #pragma unroll
    for (int c = 0; c < 16; ++c) {
        const float krr = ks[(size_t)pix*32 + c];
        const float kii = ks[(size_t)pix*32 + c + 16];
        mask8[(size_t)c*NPIX + pix] = (krr != 0.f || kii != 0.f) ? 1 : 0;
        wsf[(size_t)c*NPIX + pix] = make_float2(prev[(size_t)pix*32 + c], prev[(size_t)pix*32 + c + 16]);
    }
}

// MODE 0: out = conv(x) - x
// MODE 1: out = conv(x) - x + (mask+am)*aux ; partial += out*conj(aux)
// MODE 2: out=out2 = mask*kk + am*z - (conv(x)-x) - (mask+am)*aux ; partial += |out|^2
template<int MODE>
__global__ __launch_bounds__(512)
void conv9(const float2* __restrict__ x, const u32* __restrict__ Wd,
           float2* __restrict__ out, float2* __restrict__ out2,
           const float2* __restrict__ aux, const float* __restrict__ ks,
           const float* __restrict__ z, const uint8_t* __restrict__ mask8,
           const float* __restrict__ miu, float2* __restrict__ partials)
{
    __shared__ __align__(16) char Xs[24*24*128];   // 73728 B
    const int t = threadIdx.x;
    const int bi = blockIdx.x;
    const int i0 = (bi / 24) * 16;
    const int j0 = (bi % 24) * 16;
    const int w = t >> 6, lane = t & 63;
    const int m = lane & 15, g = lane >> 4;

    // ---- stage the full 24x24 slab once (rows i0-4..i0+19, cols j0-4..j0+19)
    for (int u = t; u < 24*24*2; u += 512) {
        const int col = u % 24;
        const int cih = (u / 24) & 1;
        const int row = u / 48;
        const int row_g = i0 - 4 + row;
        const int col_g = j0 - 4 + col;
        const bool valid = ((unsigned)row_g < MM) && ((unsigned)col_g < MM);
        float2 v[8];
        const float2* src = x + (size_t)(cih*8)*NPIX + (size_t)row_g*MM + col_g;
        #pragma unroll
        for (int e = 0; e < 8; ++e)
            v[e] = valid ? src[(size_t)e*NPIX] : make_float2(0.f, 0.f);
        u32 reh[4], rel[4], imh[4], iml[4];
        #pragma unroll
        for (int k2 = 0; k2 < 4; ++k2) {
            split_pair(v[2*k2].x, v[2*k2+1].x, reh[k2], rel[k2]);
            split_pair(v[2*k2].y, v[2*k2+1].y, imh[k2], iml[k2]);
        }
        const int c7 = (col + 4) & 7;    // == col_g & 7 (j0 % 8 == 0)
        char* pb = Xs + (size_t)(row*24 + col)*128;
        *(uint4*)(pb + (((0 + cih) ^ c7) << 4)) = make_uint4(reh[0], reh[1], reh[2], reh[3]);
        *(uint4*)(pb + (((2 + cih) ^ c7) << 4)) = make_uint4(imh[0], imh[1], imh[2], imh[3]);
        *(uint4*)(pb + (((4 + cih) ^ c7) << 4)) = make_uint4(rel[0], rel[1], rel[2], rel[3]);
        *(uint4*)(pb + (((6 + cih) ^ c7) << 4)) = make_uint4(iml[0], iml[1], iml[2], iml[3]);
    }
    __syncthreads();

    f32x4 acc[2][2];
    #pragma unroll
    for (int a = 0; a < 2; ++a)
        #pragma unroll
        for (int h = 0; h < 2; ++h) acc[a][h] = (f32x4){0.f, 0.f, 0.f, 0.f};

    // ---- 81 taps. Weight ring: WA/WB/WC (3 taps deep, global->reg).
    //      X fragments: XA/XB (1 tap ahead, LDS->reg).
    const char* wlp = (const char*)Wd + (lane << 4);
    short8 WA[4], WB[4], WC[4], XA[4], XB[4];
    char* xptr = Xs + (size_t)((2*w)*24 + m)*128;   // tap (p=0,q=0) base for this wave
    int qn = 0;                                      // q of tap being loaded next
    int c7n = (m + 4) & 7;                           // swizzle key of that tap

    // XN[0]/[1]: hi frags grp0/grp1 ; XN[2]/[3]: lo frags grp0/grp1
    #define LOADX(XN) do {                                                   \
        const int sw0_ = ((g ^ c7n) << 4);                                   \
        const int sw1_ = (((4 + g) ^ c7n) << 4);                             \
        XN[0] = *(const short8*)(xptr + sw0_);                               \
        XN[1] = *(const short8*)(xptr + 3072 + sw0_);                        \
        XN[2] = *(const short8*)(xptr + sw1_);                               \
        XN[3] = *(const short8*)(xptr + 3072 + sw1_);                        \
        const bool wr_ = (qn == 8);                                          \
        xptr += wr_ ? 2048 : 128;                                            \
        qn   = wr_ ? 0 : qn + 1;                                             \
        c7n  = wr_ ? c7n : ((c7n + 1) & 7);                                  \
    } while (0)

    #define LOADW(WS, OFF) do {                                              \
        WS[0] = *(const short8*)(wlp + (OFF));                               \
        WS[1] = *(const short8*)(wlp + (OFF) + 1024);                        \
        WS[2] = *(const short8*)(wlp + (OFF) + 2048);                        \
        WS[3] = *(const short8*)(wlp + (OFF) + 3072);                        \
    } while (0)

    // interleaved: 4 independent acc chains, dep distance 4
    #define MFMAS(XC, WS) do {                                               \
        acc[0][0] = __builtin_amdgcn_mfma_f32_16x16x32_bf16(WS[0], XC[0], acc[0][0], 0, 0, 0); \
        acc[1][0] = __builtin_amdgcn_mfma_f32_16x16x32_bf16(WS[0], XC[1], acc[1][0], 0, 0, 0); \
        acc[0][1] = __builtin_amdgcn_mfma_f32_16x16x32_bf16(WS[1], XC[0], acc[0][1], 0, 0, 0); \
        acc[1][1] = __builtin_amdgcn_mfma_f32_16x16x32_bf16(WS[1], XC[1], acc[1][1], 0, 0, 0); \
        acc[0][0] = __builtin_amdgcn_mfma_f32_16x16x32_bf16(WS[2], XC[0], acc[0][0], 0, 0, 0); \
        acc[1][0] = __builtin_amdgcn_mfma_f32_16x16x32_bf16(WS[2], XC[1], acc[1][0], 0, 0, 0); \
        acc[0][1] = __builtin_amdgcn_mfma_f32_16x16x32_bf16(WS[3], XC[0], acc[0][1], 0, 0, 0); \
        acc[1][1] = __builtin_amdgcn_mfma_f32_16x16x32_bf16(WS[3], XC[1], acc[1][1], 0, 0, 0); \
        acc[0][0] = __builtin_amdgcn_mfma_f32_16x16x32_bf16(WS[0], XC[2], acc[0][0], 0, 0, 0); \
        acc[1][0] = __builtin_amdgcn_mfma_f32_16x16x32_bf16(WS[0], XC[3], acc[1][0], 0, 0, 0); \
        acc[0][1] = __builtin_amdgcn_mfma_f32_16x16x32_bf16(WS[1], XC[2], acc[0][1], 0, 0, 0); \
        acc[1][1] = __builtin_amdgcn_mfma_f32_16x16x32_bf16(WS[1], XC[3], acc[1][1], 0, 0, 0); \
    } while (0)

    LOADW(WA, 0);          // tap 0
    LOADW(WB, 4096);       // tap 1
    LOADW(WC, 8192);       // tap 2
    wlp += 3*4096;         // wlp -> tap 3
    LOADX(XA);             // tap 0

    // taps 0..77, 13 x 6; tap t+i uses ring slot (i%3+...) pattern A,B,C,A,B,C
    #pragma unroll 1
    for (int it6 = 0; it6 < 13; ++it6) {
        LOADX(XB); MFMAS(XA, WA); LOADW(WA, 0);        // tap t   ; prefetch t+3
        LOADX(XA); MFMAS(XB, WB); LOADW(WB, 4096);     // tap t+1 ; prefetch t+4
        LOADX(XB); MFMAS(XA, WC); LOADW(WC, 8192);     // tap t+2 ; prefetch t+5
        LOADX(XA); MFMAS(XB, WA); LOADW(WA, 12288);    // tap t+3 ; prefetch t+6
        LOADX(XB); MFMAS(XA, WB); LOADW(WB, 16384);    // tap t+4 ; prefetch t+7
        LOADX(XA); MFMAS(XB, WC); LOADW(WC, 20480);    // tap t+5 ; prefetch t+8
        wlp += 6*4096;
    }
    // tail: taps 78 (WA, XA), 79 (WB), 80 (WC)
    LOADX(XB); MFMAS(XA, WA);   // tap 78
    LOADX(XA); MFMAS(XB, WB);   // tap 79
    MFMAS(XA, WC);              // tap 80

    #undef LOADX
    #undef LOADW
    #undef MFMAS

    // ---- epilogue: C/D col = lane&15 = pixel, row = g*4+j = co
    const float am = (MODE >= 1) ? fabsf(miu[0]) : 0.f;
    float2 part = make_float2(0.f, 0.f);
    #pragma unroll
    for (int grp = 0; grp < 2; ++grp) {
        const int rowo = i0 + 2*w + grp;
        const int colo = j0 + m;
        const int pix = rowo*MM + colo;
        #pragma unroll
        for (int j = 0; j < 4; ++j) {
            const int co = g*4 + j;
            const size_t idx = (size_t)co*NPIX + pix;
            const float rr = acc[grp][0][j], ii = acc[grp][1][j];
            if (MODE == 0) {
                const float2 xc = x[idx];
                out[idx] = make_float2(rr - xc.x, ii - xc.y);
            } else if (MODE == 1) {
                const float2 tc = x[idx];
                const float2 pc = aux[idx];
                const float mv = mask8[idx] ? 1.f : 0.f;
                const float qr = rr - tc.x + (mv + am)*pc.x;
                const float qi = ii - tc.y + (mv + am)*pc.y;
                out[idx] = make_float2(qr, qi);
                part.x += qr*pc.x + qi*pc.y;
                part.y += qi*pc.x - qr*pc.y;
            } else {
                const float2 tc = x[idx];
                const float2 wc = aux[idx];
                const float mv = mask8[idx] ? 1.f : 0.f;
                const float kr_ = ks[(size_t)pix*32 + co];
                const float ki_ = ks[(size_t)pix*32 + co + 16];
                const float zr  = z[(size_t)pix*32 + co];
                const float zi  = z[(size_t)pix*32 + co + 16];
                const float pr = mv*kr_ + am*zr - (rr - tc.x) - (mv + am)*wc.x;
                const float pi = mv*ki_ + am*zi - (ii - tc.y) - (mv + am)*wc.y;
                out[idx]  = make_float2(pr, pi);
                out2[idx] = make_float2(pr, pi);
                part.x += pr*pr + pi*pi;
            }
        }
    }
    if (MODE >= 1) {
        __syncthreads();
        part = block_reduce2(part);
        if (t == 0) partials[bi] = part;
    }
}

__global__ void finalize_rr(const float2* __restrict__ partials, float* __restrict__ scal, int n) {
    float2 s = make_float2(0.f, 0.f);
    for (int i = threadIdx.x; i < n; i += blockDim.x) { s.x += partials[i].x; s.y += partials[i].y; }
    s = block_reduce2(s);
    if (threadIdx.x == 0) scal[0] = s.x;
}

__global__ void finalize_alpha(const float2* __restrict__ partials, float* __restrict__ scal, int n) {
    float2 s = make_float2(0.f, 0.f);
    for (int i = threadIdx.x; i < n; i += blockDim.x) { s.x += partials[i].x; s.y += partials[i].y; }
    s = block_reduce2(s);
    if (threadIdx.x == 0) {
        const float rr = scal[0];
        const float d = s.x*s.x + s.y*s.y;
        scal[1] =  rr * s.x / d;
        scal[2] = -rr * s.y / d;
    }
}

__global__ void update_br(float2* __restrict__ b, const float2* __restrict__ p,
                          float2* __restrict__ r, const float2* __restrict__ q,
                          const float* __restrict__ scal, float2* __restrict__ partials) {
    const float ar = scal[1], ai = scal[2];
    float2 s = make_float2(0.f, 0.f);
    for (int e = blockIdx.x*256 + threadIdx.x; e < N2; e += NRED*256) {
        const float2 pv = p[e], qv = q[e];
        float2 bv = b[e], rv = r[e];
        bv.x += ar*pv.x - ai*pv.y;
        bv.y += ar*pv.y + ai*pv.x;
        rv.x -= ar*qv.x - ai*qv.y;
        rv.y -= ar*qv.y + ai*qv.x;
        b[e] = bv; r[e] = rv;
        s.x += rv.x*rv.x + rv.y*rv.y;
    }
    s = block_reduce2(s);
    if (threadIdx.x == 0) partials[blockIdx.x] = s;
}

__global__ void finalize_beta(const float2* __restrict__ partials, float* __restrict__ scal) {
    float2 v = partials[threadIdx.x];
    v = block_reduce2(v);
    if (threadIdx.x == 0) {
        const float rn = v.x;
        scal[3] = rn / scal[0];
        scal[0] = rn;
    }
}

__global__ void update_p(float2* __restrict__ p, const float2* __restrict__ r,
                         const float* __restrict__ scal) {
    const float beta = scal[3];
    const int e = blockIdx.x*256 + threadIdx.x;
    if (e < N2) {
        const float2 pv = p[e], rv = r[e];
        p[e] = make_float2(rv.x + beta*pv.x, rv.y + beta*pv.y);
    }
}

__global__ void pack_out(const float2* __restrict__ b, float* __restrict__ out) {
    const int e = blockIdx.x*256 + threadIdx.x;
    if (e >= 32*NPIX) return;
    const int pix = e >> 5;
    const int cc  = e & 31;
    const float2 v = b[(size_t)(cc & 15)*NPIX + pix];
    out[e] = (cc < 16) ? v.x : v.y;
}

extern "C" void kernel_launch(void* const* d_in, const int* in_sizes, int n_in,
                              void* d_out, int out_size, void* d_ws, size_t ws_size,
                              hipStream_t stream) {
    const float* z    = (const float*)d_in[0];
    const float* ks   = (const float*)d_in[1];
    const float* kr   = (const float*)d_in[2];
    const float* ki   = (const float*)d_in[3];
    const float* prev = (const float*)d_in[5];
    const float* miu  = (const float*)d_in[6];
    float* out = (float*)d_out;

    char* w = (char*)d_ws;
    const size_t FB = (size_t)N2 * sizeof(float2);
    float2* wsf = (float2*)w; w += FB;    // b (in-place)
    float2* pf  = (float2*)w; w += FB;
    float2* rf  = (float2*)w; w += FB;
    float2* qf  = (float2*)w; w += FB;
    float2* tf  = (float2*)w; w += FB;
    u32* wbuf   = (u32*)w;   w += (size_t)2*324*256*sizeof(u32);
    uint8_t* mask8 = (uint8_t*)w; w += (size_t)N2;
    w = (char*)(((uintptr_t)w + 255) & ~(uintptr_t)255);
    float2* partials = (float2*)w; w += (size_t)NCBLK * sizeof(float2);
    float*  scal     = (float*)w;

    const u32* wbF = wbuf;
    const u32* wbB = wbuf + (size_t)324*256;

    prep_weights<<<81, 256, 0, stream>>>(kr, ki, wbuf);
    prep_fields<<<576, 256, 0, stream>>>(ks, prev, wsf, mask8);

    conv9<0><<<NCBLK, 512, 0, stream>>>(wsf, wbF, tf, nullptr, nullptr, nullptr, nullptr, nullptr, nullptr, nullptr);
    conv9<2><<<NCBLK, 512, 0, stream>>>(tf, wbB, pf, rf, wsf, ks, z, mask8, miu, partials);
    finalize_rr<<<1, 256, 0, stream>>>(partials, scal, NCBLK);

    for (int it = 0; it < 10; ++it) {
        conv9<0><<<NCBLK, 512, 0, stream>>>(pf, wbF, tf, nullptr, nullptr, nullptr, nullptr, nullptr, nullptr, nullptr);
        conv9<1><<<NCBLK, 512, 0, stream>>>(tf, wbB, qf, nullptr, pf, nullptr, nullptr, mask8, miu, partials);
        finalize_alpha<<<1, 256, 0, stream>>>(partials, scal, NCBLK);
        update_br<<<NRED, 256, 0, stream>>>(wsf, pf, rf, qf, scal, partials);
        finalize_beta<<<1, NRED, 0, stream>>>(partials, scal);
        update_p<<<9216, 256, 0, stream>>>(pf, rf, scal);
    }

    pack_out<<<18432, 256, 0, stream>>>(wsf, out);
}